// Round 11
// baseline (73.628 us; speedup 1.0000x reference)
//
#include <hip/hip_runtime.h>
#include <hip/hip_bf16.h>

typedef __attribute__((ext_vector_type(8))) short short8;
typedef __attribute__((ext_vector_type(4))) float f32x4;
typedef unsigned long long ull;

#define N1 768
#define N2 768
#define LL 128
#define NS 30

// float -> bf16 bits, round-to-nearest-even (proven rounds 1-9)
__device__ __forceinline__ unsigned short f2b(float f) {
  unsigned int u = __float_as_uint(f);
  unsigned int r = (u + 0x7fffu + ((u >> 16) & 1u)) >> 16;
  return (unsigned short)r;
}

// ---------------------------------------------------------------------------
// prep: block 0: S = A@A^T as bf16 table (stride 32) + Sdiag (f32).
//       blocks 1..32: w = sigmoid(W) (f32 + bf16).
// ---------------------------------------------------------------------------
__global__ void prep_kernel(const float* __restrict__ A, const float* __restrict__ w_vec,
                            float* __restrict__ wf, unsigned short* __restrict__ wb,
                            float* __restrict__ Sdiag, unsigned short* __restrict__ Sbg) {
  int b = blockIdx.x, t = threadIdx.x;
  if (b == 0) {
    for (int idx = t; idx < NS * NS; idx += 256) {
      int i = idx / NS, j = idx - i * NS;
      float acc = 0.f;
#pragma unroll
      for (int k = 0; k < 16; ++k) acc += A[i * 16 + k] * A[j * 16 + k];
      Sbg[i * 32 + j] = f2b(acc);
      if (i == j) Sdiag[i] = acc;
    }
  } else {
    int base = (b - 1) * 512;
#pragma unroll
    for (int k = 0; k < 2; ++k) {
      int idx = base + k * 256 + t;
      int l = idx >> 7, mm = idx & (LL - 1);
      float sig;
      if (l == mm) {
        sig = 0.5f;
      } else {
        int hi = l > mm ? l : mm, lo = l > mm ? mm : l;
        sig = 1.f / (1.f + expf(-w_vec[hi * (hi - 1) / 2 + lo]));
      }
      wf[idx] = sig;
      wb[idx] = f2b(sig);
    }
  }
}

// ---------------------------------------------------------------------------
// norm: one block (128 thr) per 8 rows (round-8 version, kept).
// ---------------------------------------------------------------------------
__global__ __launch_bounds__(128) void norm_kernel(
    const int* __restrict__ X1, const int* __restrict__ X2,
    const float* __restrict__ Sdiag, const float* __restrict__ wf,
    float* __restrict__ inv1, float* __restrict__ inv2,
    const float* __restrict__ a_ptr) {
  __shared__ __align__(16) float d[8][LL];
  __shared__ float wsum[2][8];
  const int t = threadIdx.x;
  const int r0 = blockIdx.x * 8;
#pragma unroll
  for (int r = 0; r < 8; ++r) {
    int row = r0 + r;
    const int* X = (row < N1) ? (X1 + row * LL) : (X2 + (row - N1) * LL);
    d[r][t] = Sdiag[X[t]];
  }
  __syncthreads();
  const float4* w4 = reinterpret_cast<const float4*>(wf + t * LL);
  float s[8] = {0.f, 0.f, 0.f, 0.f, 0.f, 0.f, 0.f, 0.f};
#pragma unroll 8
  for (int q = 0; q < 32; ++q) {
    float4 wv = w4[q];
#pragma unroll
    for (int r = 0; r < 8; ++r) {
      float4 dd = *reinterpret_cast<const float4*>(&d[r][q * 4]);
      s[r] += wv.x * dd.x + wv.y * dd.y + wv.z * dd.z + wv.w * dd.w;
    }
  }
#pragma unroll
  for (int r = 0; r < 8; ++r) {
    float v = s[r] * d[r][t];
    v += __shfl_xor(v, 1);
    v += __shfl_xor(v, 2);
    v += __shfl_xor(v, 4);
    v += __shfl_xor(v, 8);
    v += __shfl_xor(v, 16);
    v += __shfl_xor(v, 32);
    if ((t & 63) == 0) wsum[t >> 6][r] = v;
  }
  __syncthreads();
  if (t < 8) {
    int row = r0 + t;
    float k = wsum[0][t] + wsum[1][t];
    if (row < N1) inv1[row] = a_ptr[0] * a_ptr[0] / sqrtf(k);
    else inv2[row - N1] = 1.f / sqrtf(k);
  }
}

// ---------------------------------------------------------------------------
// main: one block = 16x16 output tile, 512 threads (8 waves), ~72.4 KB LDS
//   -> 2 blocks/CU.
//  phase2 (round-7/9 proven): direct gather V-build from stride-32 bf16
//    S-table; thread owns pair p2=t&255, l-half h2=t>>8.
//  phase3: 2-way l-split. wave (lg2=wave&1, ph=wave>>1) owns 64 W-rows
//    x 64 pairs. W slice = wreg[4][4] = 64 VGPRs via ASM VOLATILE
//    global_load_dwordx4 (un-sinkable), FOLLOWED BY EXPLICIT
//    s_waitcnt vmcnt(0) + sched_barrier(0)  (round-10 NaN: compiler does
//    not track inline-asm vmcnt, so nothing else drains these loads).
// ---------------------------------------------------------------------------
__global__ __launch_bounds__(512, 4) void main_kernel(
    const int* __restrict__ X1, const int* __restrict__ X2,
    const unsigned short* __restrict__ wbg, const unsigned short* __restrict__ Sbg,
    const float* __restrict__ inv1, const float* __restrict__ inv2,
    float* __restrict__ out) {
  __shared__ __align__(16) unsigned short sV[256 * LL];  // 64 KB, swizzled
  __shared__ __align__(16) unsigned short sSb[960];      // 1920 B S-table (stride 32)
  __shared__ __align__(16) unsigned char x1B[16 * 144];  // bytes [row][l]
  __shared__ __align__(16) unsigned char x2B[16 * 144];
  __shared__ __align__(16) float red[2 * 256];           // cross-lg2 partials

  const int t = threadIdx.x;
  const int lane = t & 63, wave = t >> 6;
  const int m = lane & 15, kg = lane >> 4;
  const int i0 = blockIdx.y * 16, j0 = blockIdx.x * 16;
  char* sVb = reinterpret_cast<char*>(sV);

  // ---- per-output normalization scalars ----
  float iv1v = 0.f, iv2v = 0.f;
  if (t < 256) {
    iv1v = inv1[i0 + (t >> 4)];
    iv2v = inv2[j0 + (t & 15)];
  }

  // ---- stage bf16 S-table (1920 B = 120 uint4) ----
  if (t < 120) reinterpret_cast<uint4*>(sSb)[t] = reinterpret_cast<const uint4*>(Sbg)[t];

  // ---- stage X rows as bytes [row][l], stride 144 (16-aligned) ----
  if (t < 256) {
    int row = t >> 4, seg = t & 15;
    const int4* p1 = reinterpret_cast<const int4*>(X1 + (i0 + row) * LL + seg * 8);
    int4 a0 = p1[0], a1 = p1[1];
    ull v = 0;
    v |= (ull)(a0.x & 0xff);
    v |= (ull)(a0.y & 0xff) << 8;
    v |= (ull)(a0.z & 0xff) << 16;
    v |= (ull)(a0.w & 0xff) << 24;
    v |= (ull)(a1.x & 0xff) << 32;
    v |= (ull)(a1.y & 0xff) << 40;
    v |= (ull)(a1.z & 0xff) << 48;
    v |= (ull)(a1.w & 0xff) << 56;
    *reinterpret_cast<ull*>(x1B + row * 144 + seg * 8) = v;
    const int4* p2p = reinterpret_cast<const int4*>(X2 + (j0 + row) * LL + seg * 8);
    int4 b0 = p2p[0], b1 = p2p[1];
    ull u = 0;
    u |= (ull)(b0.x & 0xff);
    u |= (ull)(b0.y & 0xff) << 8;
    u |= (ull)(b0.z & 0xff) << 16;
    u |= (ull)(b0.w & 0xff) << 24;
    u |= (ull)(b1.x & 0xff) << 32;
    u |= (ull)(b1.y & 0xff) << 40;
    u |= (ull)(b1.z & 0xff) << 48;
    u |= (ull)(b1.w & 0xff) << 56;
    *reinterpret_cast<ull*>(x2B + row * 144 + seg * 8) = u;
  }
  __syncthreads();

  // ---- phase 2: gather V-build. thread owns pair p2=t&255, l-half h2 ----
  {
    const int p2 = t & 255;
    const int h2 = t >> 8;
    const char* a1p = reinterpret_cast<const char*>(x1B) + (p2 >> 4) * 144 + 64 * h2;
    const char* a2p = reinterpret_cast<const char*>(x2B) + (p2 & 15) * 144 + 64 * h2;
    uint4 A0 = *reinterpret_cast<const uint4*>(a1p);
    uint4 A1 = *reinterpret_cast<const uint4*>(a1p + 16);
    uint4 A2 = *reinterpret_cast<const uint4*>(a1p + 32);
    uint4 A3 = *reinterpret_cast<const uint4*>(a1p + 48);
    uint4 B0 = *reinterpret_cast<const uint4*>(a2p);
    uint4 B1 = *reinterpret_cast<const uint4*>(a2p + 16);
    uint4 B2 = *reinterpret_cast<const uint4*>(a2p + 32);
    uint4 B3 = *reinterpret_cast<const uint4*>(a2p + 48);
    const int swz = (p2 & 7) << 4;
    char* wbase = sVb + p2 * 256;
#define QUAD(u1, u2, w0, w1)                                                        \
    {                                                                               \
      unsigned a0_ = (u1) & 255u, a1_ = ((u1) >> 8) & 255u;                         \
      unsigned a2_ = ((u1) >> 16) & 255u, a3_ = (u1) >> 24;                         \
      unsigned b0_ = (u2) & 255u, b1_ = ((u2) >> 8) & 255u;                         \
      unsigned b2_ = ((u2) >> 16) & 255u, b3_ = (u2) >> 24;                         \
      unsigned g0 = sSb[(a0_ << 5) | b0_];                                          \
      unsigned g1 = sSb[(a1_ << 5) | b1_];                                          \
      unsigned g2 = sSb[(a2_ << 5) | b2_];                                          \
      unsigned g3 = sSb[(a3_ << 5) | b3_];                                          \
      w0 = g0 | (g1 << 16);                                                         \
      w1 = g2 | (g3 << 16);                                                         \
    }
#define OCT(o, U1a, U2a, U1b, U2b)                                                  \
    {                                                                               \
      uint4 pk;                                                                     \
      QUAD(U1a, U2a, pk.x, pk.y)                                                    \
      QUAD(U1b, U2b, pk.z, pk.w)                                                    \
      *reinterpret_cast<uint4*>(wbase + ((128 * h2 + 16 * (o)) ^ swz)) = pk;        \
    }
    OCT(0, A0.x, B0.x, A0.y, B0.y)
    OCT(1, A0.z, B0.z, A0.w, B0.w)
    OCT(2, A1.x, B1.x, A1.y, B1.y)
    OCT(3, A1.z, B1.z, A1.w, B1.w)
    OCT(4, A2.x, B2.x, A2.y, B2.y)
    OCT(5, A2.z, B2.z, A2.w, B2.w)
    OCT(6, A3.x, B3.x, A3.y, B3.y)
    OCT(7, A3.z, B3.z, A3.w, B3.w)
#undef OCT
#undef QUAD
  }

  // ---- W slice (64 rows) into 64 VGPRs via VOLATILE asm loads, then an
  //      EXPLICIT vmcnt(0) drain + scheduler fence (round-10 fix) ----
  const int lg2 = wave & 1, ph = wave >> 1;
  short8 wreg[4][4];
  {
    const char* wby = reinterpret_cast<const char*>(wbg) + (lg2 * 64 + m) * 256 + kg * 16;
#pragma unroll
    for (int lt = 0; lt < 4; ++lt)
#pragma unroll
      for (int kk = 0; kk < 4; ++kk) {
        const char* addr = wby + lt * 16 * 256 + kk * 64;
        asm volatile("global_load_dwordx4 %0, %1, off"
                     : "=v"(wreg[lt][kk])
                     : "v"(addr));
      }
    asm volatile("s_waitcnt vmcnt(0)" ::: "memory");
    __builtin_amdgcn_sched_barrier(0);
  }
  __syncthreads();

  // ---- phase 3: E^T slice = W[lg2's 64 rows] @ V^T, folded epilogue ----
#pragma unroll
  for (int pt = 0; pt < 4; ++pt) {
    const int p = ph * 64 + pt * 16 + m;
    const int sw = (p & 7) << 4;
    const char* base = sVb + p * 256;
    short8 bv[4];
#pragma unroll
    for (int kk = 0; kk < 4; ++kk)
      bv[kk] = *reinterpret_cast<const short8*>(base + ((kk * 64 + kg * 16) ^ sw));
    float kp = 0.f;
#pragma unroll
    for (int lt = 0; lt < 4; ++lt) {
      f32x4 acc = {0.f, 0.f, 0.f, 0.f};
#pragma unroll
      for (int kk = 0; kk < 4; ++kk)
        acc = __builtin_amdgcn_mfma_f32_16x16x32_bf16(wreg[lt][kk], bv[kk], acc, 0, 0, 0);
      uint2 vv = *reinterpret_cast<const uint2*>(
          base + ((128 * lg2 + 32 * lt + 8 * kg) ^ sw));
      kp += acc[0] * __uint_as_float(vv.x << 16) + acc[1] * __uint_as_float(vv.x & 0xffff0000u) +
            acc[2] * __uint_as_float(vv.y << 16) + acc[3] * __uint_as_float(vv.y & 0xffff0000u);
    }
    kp += __shfl_xor(kp, 16);
    kp += __shfl_xor(kp, 32);
    if (kg == 0) red[lg2 * 256 + p] = kp;
  }
  __syncthreads();

  // ---- final: cross-lg2 sum, fused normalization, store ----
  if (t < 256) {
    float s = red[t] + red[256 + t];
    out[(i0 + (t >> 4)) * N2 + j0 + (t & 15)] = s * iv1v * iv2v;
  }
}

// ---------------------------------------------------------------------------
extern "C" void kernel_launch(void* const* d_in, const int* in_sizes, int n_in,
                              void* d_out, int out_size, void* d_ws, size_t ws_size,
                              hipStream_t stream) {
  const int* X1 = (const int*)d_in[0];
  const int* X2 = (const int*)d_in[1];
  const float* a = (const float*)d_in[2];
  const float* A = (const float*)d_in[3];
  const float* w_vec = (const float*)d_in[4];
  float* out = (float*)d_out;

  char* ws = (char*)d_ws;
  float* wf = (float*)(ws + 0);                        // 64 KB
  unsigned short* wb = (unsigned short*)(ws + 65536);  // 32 KB
  float* Sdiag = (float*)(ws + 98304);                 // 128 B
  unsigned short* Sbg = (unsigned short*)(ws + 98432); // 1920 B
  float* inv1 = (float*)(ws + 100352);                 // 3 KB
  float* inv2 = (float*)(ws + 103424);                 // 3 KB

  prep_kernel<<<33, 256, 0, stream>>>(A, w_vec, wf, wb, Sdiag, Sbg);
  norm_kernel<<<(N1 + N2) / 8, 128, 0, stream>>>(X1, X2, Sdiag, wf, inv1, inv2, a);
  main_kernel<<<dim3(N2 / 16, N1 / 16), 512, 0, stream>>>(X1, X2, wb, Sbg, inv1, inv2, out);
}

// Round 12
// 67.434 us; speedup vs baseline: 1.0919x; 1.0919x over previous
//
#include <hip/hip_runtime.h>
#include <hip/hip_bf16.h>

typedef __attribute__((ext_vector_type(8))) short short8;
typedef __attribute__((ext_vector_type(4))) float f32x4;
typedef unsigned long long ull;

#define N1 768
#define N2 768
#define LL 128
#define NS 30

// float -> bf16 bits, round-to-nearest-even (proven rounds 1-11)
__device__ __forceinline__ unsigned short f2b(float f) {
  unsigned int u = __float_as_uint(f);
  unsigned int r = (u + 0x7fffu + ((u >> 16) & 1u)) >> 16;
  return (unsigned short)r;
}

// ---------------------------------------------------------------------------
// prep: block 0: S = A@A^T as bf16 table (stride 32) + Sdiag (f32).
//       blocks 1..32: w = sigmoid(W) (f32 + bf16).
// ---------------------------------------------------------------------------
__global__ void prep_kernel(const float* __restrict__ A, const float* __restrict__ w_vec,
                            float* __restrict__ wf, unsigned short* __restrict__ wb,
                            float* __restrict__ Sdiag, unsigned short* __restrict__ Sbg) {
  int b = blockIdx.x, t = threadIdx.x;
  if (b == 0) {
    for (int idx = t; idx < NS * NS; idx += 256) {
      int i = idx / NS, j = idx - i * NS;
      float acc = 0.f;
#pragma unroll
      for (int k = 0; k < 16; ++k) acc += A[i * 16 + k] * A[j * 16 + k];
      Sbg[i * 32 + j] = f2b(acc);
      if (i == j) Sdiag[i] = acc;
    }
  } else {
    int base = (b - 1) * 512;
#pragma unroll
    for (int k = 0; k < 2; ++k) {
      int idx = base + k * 256 + t;
      int l = idx >> 7, mm = idx & (LL - 1);
      float sig;
      if (l == mm) {
        sig = 0.5f;
      } else {
        int hi = l > mm ? l : mm, lo = l > mm ? mm : l;
        sig = 1.f / (1.f + expf(-w_vec[hi * (hi - 1) / 2 + lo]));
      }
      wf[idx] = sig;
      wb[idx] = f2b(sig);
    }
  }
}

// ---------------------------------------------------------------------------
// norm: one block (128 thr) per 8 rows (round-8 version, kept).
// ---------------------------------------------------------------------------
__global__ __launch_bounds__(128) void norm_kernel(
    const int* __restrict__ X1, const int* __restrict__ X2,
    const float* __restrict__ Sdiag, const float* __restrict__ wf,
    float* __restrict__ inv1, float* __restrict__ inv2,
    const float* __restrict__ a_ptr) {
  __shared__ __align__(16) float d[8][LL];
  __shared__ float wsum[2][8];
  const int t = threadIdx.x;
  const int r0 = blockIdx.x * 8;
#pragma unroll
  for (int r = 0; r < 8; ++r) {
    int row = r0 + r;
    const int* X = (row < N1) ? (X1 + row * LL) : (X2 + (row - N1) * LL);
    d[r][t] = Sdiag[X[t]];
  }
  __syncthreads();
  const float4* w4 = reinterpret_cast<const float4*>(wf + t * LL);
  float s[8] = {0.f, 0.f, 0.f, 0.f, 0.f, 0.f, 0.f, 0.f};
#pragma unroll 8
  for (int q = 0; q < 32; ++q) {
    float4 wv = w4[q];
#pragma unroll
    for (int r = 0; r < 8; ++r) {
      float4 dd = *reinterpret_cast<const float4*>(&d[r][q * 4]);
      s[r] += wv.x * dd.x + wv.y * dd.y + wv.z * dd.z + wv.w * dd.w;
    }
  }
#pragma unroll
  for (int r = 0; r < 8; ++r) {
    float v = s[r] * d[r][t];
    v += __shfl_xor(v, 1);
    v += __shfl_xor(v, 2);
    v += __shfl_xor(v, 4);
    v += __shfl_xor(v, 8);
    v += __shfl_xor(v, 16);
    v += __shfl_xor(v, 32);
    if ((t & 63) == 0) wsum[t >> 6][r] = v;
  }
  __syncthreads();
  if (t < 8) {
    int row = r0 + t;
    float k = wsum[0][t] + wsum[1][t];
    if (row < N1) inv1[row] = a_ptr[0] * a_ptr[0] / sqrtf(k);
    else inv2[row - N1] = 1.f / sqrtf(k);
  }
}

// ---------------------------------------------------------------------------
// main: one block = 16x16 output tile, 512 threads (8 waves), ~72.4 KB LDS
//   -> 2 blocks/CU (LDS-capped at 4 waves/SIMD).
//  KEY FIX (round 12): amdgpu_waves_per_eu(4,4) pins the allocator's
//    occupancy TARGET to what LDS already caps us at. Rounds 7/8/11 proved
//    the default target is 8 waves/EU (<=64 VGPR), which made it sink plain
//    W loads (r7/8) or spill asm W outputs to scratch (r11). With the target
//    at 4 waves/EU the 128-VGPR budget fits wreg[4][4]=64 regs resident.
//  phase2 (round-7/9 proven): direct gather V-build from stride-32 bf16
//    S-table; thread owns pair p2=t&255, l-half h2=t>>8.
//  phase3: 2-way l-split. wave (lg2=wave&1, ph=wave>>1) owns 64 W-rows
//    x 64 pairs; bv redundancy 2x (128 b128/block). Folded epilogue,
//    shfl(16,32) reduce, cross-lg2 sum via red[2][256].
// ---------------------------------------------------------------------------
__global__ __attribute__((amdgpu_flat_work_group_size(512, 512),
                          amdgpu_waves_per_eu(4, 4))) void main_kernel(
    const int* __restrict__ X1, const int* __restrict__ X2,
    const unsigned short* __restrict__ wbg, const unsigned short* __restrict__ Sbg,
    const float* __restrict__ inv1, const float* __restrict__ inv2,
    float* __restrict__ out) {
  __shared__ __align__(16) unsigned short sV[256 * LL];  // 64 KB, swizzled
  __shared__ __align__(16) unsigned short sSb[960];      // 1920 B S-table (stride 32)
  __shared__ __align__(16) unsigned char x1B[16 * 144];  // bytes [row][l]
  __shared__ __align__(16) unsigned char x2B[16 * 144];
  __shared__ __align__(16) float red[2 * 256];           // cross-lg2 partials

  const int t = threadIdx.x;
  const int lane = t & 63, wave = t >> 6;
  const int m = lane & 15, kg = lane >> 4;
  const int i0 = blockIdx.y * 16, j0 = blockIdx.x * 16;
  char* sVb = reinterpret_cast<char*>(sV);

  // ---- per-output normalization scalars ----
  float iv1v = 0.f, iv2v = 0.f;
  if (t < 256) {
    iv1v = inv1[i0 + (t >> 4)];
    iv2v = inv2[j0 + (t & 15)];
  }

  // ---- stage bf16 S-table (1920 B = 120 uint4) ----
  if (t < 120) reinterpret_cast<uint4*>(sSb)[t] = reinterpret_cast<const uint4*>(Sbg)[t];

  // ---- stage X rows as bytes [row][l], stride 144 (16-aligned) ----
  if (t < 256) {
    int row = t >> 4, seg = t & 15;
    const int4* p1 = reinterpret_cast<const int4*>(X1 + (i0 + row) * LL + seg * 8);
    int4 a0 = p1[0], a1 = p1[1];
    ull v = 0;
    v |= (ull)(a0.x & 0xff);
    v |= (ull)(a0.y & 0xff) << 8;
    v |= (ull)(a0.z & 0xff) << 16;
    v |= (ull)(a0.w & 0xff) << 24;
    v |= (ull)(a1.x & 0xff) << 32;
    v |= (ull)(a1.y & 0xff) << 40;
    v |= (ull)(a1.z & 0xff) << 48;
    v |= (ull)(a1.w & 0xff) << 56;
    *reinterpret_cast<ull*>(x1B + row * 144 + seg * 8) = v;
    const int4* p2p = reinterpret_cast<const int4*>(X2 + (j0 + row) * LL + seg * 8);
    int4 b0 = p2p[0], b1 = p2p[1];
    ull u = 0;
    u |= (ull)(b0.x & 0xff);
    u |= (ull)(b0.y & 0xff) << 8;
    u |= (ull)(b0.z & 0xff) << 16;
    u |= (ull)(b0.w & 0xff) << 24;
    u |= (ull)(b1.x & 0xff) << 32;
    u |= (ull)(b1.y & 0xff) << 40;
    u |= (ull)(b1.z & 0xff) << 48;
    u |= (ull)(b1.w & 0xff) << 56;
    *reinterpret_cast<ull*>(x2B + row * 144 + seg * 8) = u;
  }
  __syncthreads();

  // ---- phase 2: gather V-build. thread owns pair p2=t&255, l-half h2 ----
  {
    const int p2 = t & 255;
    const int h2 = t >> 8;
    const char* a1p = reinterpret_cast<const char*>(x1B) + (p2 >> 4) * 144 + 64 * h2;
    const char* a2p = reinterpret_cast<const char*>(x2B) + (p2 & 15) * 144 + 64 * h2;
    uint4 A0 = *reinterpret_cast<const uint4*>(a1p);
    uint4 A1 = *reinterpret_cast<const uint4*>(a1p + 16);
    uint4 A2 = *reinterpret_cast<const uint4*>(a1p + 32);
    uint4 A3 = *reinterpret_cast<const uint4*>(a1p + 48);
    uint4 B0 = *reinterpret_cast<const uint4*>(a2p);
    uint4 B1 = *reinterpret_cast<const uint4*>(a2p + 16);
    uint4 B2 = *reinterpret_cast<const uint4*>(a2p + 32);
    uint4 B3 = *reinterpret_cast<const uint4*>(a2p + 48);
    const int swz = (p2 & 7) << 4;
    char* wbase = sVb + p2 * 256;
#define QUAD(u1, u2, w0, w1)                                                        \
    {                                                                               \
      unsigned a0_ = (u1) & 255u, a1_ = ((u1) >> 8) & 255u;                         \
      unsigned a2_ = ((u1) >> 16) & 255u, a3_ = (u1) >> 24;                         \
      unsigned b0_ = (u2) & 255u, b1_ = ((u2) >> 8) & 255u;                         \
      unsigned b2_ = ((u2) >> 16) & 255u, b3_ = (u2) >> 24;                         \
      unsigned g0 = sSb[(a0_ << 5) | b0_];                                          \
      unsigned g1 = sSb[(a1_ << 5) | b1_];                                          \
      unsigned g2 = sSb[(a2_ << 5) | b2_];                                          \
      unsigned g3 = sSb[(a3_ << 5) | b3_];                                          \
      w0 = g0 | (g1 << 16);                                                         \
      w1 = g2 | (g3 << 16);                                                         \
    }
#define OCT(o, U1a, U2a, U1b, U2b)                                                  \
    {                                                                               \
      uint4 pk;                                                                     \
      QUAD(U1a, U2a, pk.x, pk.y)                                                    \
      QUAD(U1b, U2b, pk.z, pk.w)                                                    \
      *reinterpret_cast<uint4*>(wbase + ((128 * h2 + 16 * (o)) ^ swz)) = pk;        \
    }
    OCT(0, A0.x, B0.x, A0.y, B0.y)
    OCT(1, A0.z, B0.z, A0.w, B0.w)
    OCT(2, A1.x, B1.x, A1.y, B1.y)
    OCT(3, A1.z, B1.z, A1.w, B1.w)
    OCT(4, A2.x, B2.x, A2.y, B2.y)
    OCT(5, A2.z, B2.z, A2.w, B2.w)
    OCT(6, A3.x, B3.x, A3.y, B3.y)
    OCT(7, A3.z, B3.z, A3.w, B3.w)
#undef OCT
#undef QUAD
  }

  // ---- W slice (64 rows) into 64 VGPRs: plain loads; the waves_per_eu(4,4)
  //      pressure target (128 VGPR) lets them stay resident ----
  const int lg2 = wave & 1, ph = wave >> 1;
  short8 wreg[4][4];
  {
    const char* wby = reinterpret_cast<const char*>(wbg) + (lg2 * 64 + m) * 256 + kg * 16;
#pragma unroll
    for (int lt = 0; lt < 4; ++lt)
#pragma unroll
      for (int kk = 0; kk < 4; ++kk)
        wreg[lt][kk] = *reinterpret_cast<const short8*>(wby + lt * 16 * 256 + kk * 64);
  }
  __syncthreads();

  // ---- phase 3: E^T slice = W[lg2's 64 rows] @ V^T, folded epilogue ----
#pragma unroll
  for (int pt = 0; pt < 4; ++pt) {
    const int p = ph * 64 + pt * 16 + m;
    const int sw = (p & 7) << 4;
    const char* base = sVb + p * 256;
    short8 bv[4];
#pragma unroll
    for (int kk = 0; kk < 4; ++kk)
      bv[kk] = *reinterpret_cast<const short8*>(base + ((kk * 64 + kg * 16) ^ sw));
    float kp = 0.f;
#pragma unroll
    for (int lt = 0; lt < 4; ++lt) {
      f32x4 acc = {0.f, 0.f, 0.f, 0.f};
#pragma unroll
      for (int kk = 0; kk < 4; ++kk)
        acc = __builtin_amdgcn_mfma_f32_16x16x32_bf16(wreg[lt][kk], bv[kk], acc, 0, 0, 0);
      uint2 vv = *reinterpret_cast<const uint2*>(
          base + ((128 * lg2 + 32 * lt + 8 * kg) ^ sw));
      kp += acc[0] * __uint_as_float(vv.x << 16) + acc[1] * __uint_as_float(vv.x & 0xffff0000u) +
            acc[2] * __uint_as_float(vv.y << 16) + acc[3] * __uint_as_float(vv.y & 0xffff0000u);
    }
    kp += __shfl_xor(kp, 16);
    kp += __shfl_xor(kp, 32);
    if (kg == 0) red[lg2 * 256 + p] = kp;
  }
  __syncthreads();

  // ---- final: cross-lg2 sum, fused normalization, store ----
  if (t < 256) {
    float s = red[t] + red[256 + t];
    out[(i0 + (t >> 4)) * N2 + j0 + (t & 15)] = s * iv1v * iv2v;
  }
}

// ---------------------------------------------------------------------------
extern "C" void kernel_launch(void* const* d_in, const int* in_sizes, int n_in,
                              void* d_out, int out_size, void* d_ws, size_t ws_size,
                              hipStream_t stream) {
  const int* X1 = (const int*)d_in[0];
  const int* X2 = (const int*)d_in[1];
  const float* a = (const float*)d_in[2];
  const float* A = (const float*)d_in[3];
  const float* w_vec = (const float*)d_in[4];
  float* out = (float*)d_out;

  char* ws = (char*)d_ws;
  float* wf = (float*)(ws + 0);                        // 64 KB
  unsigned short* wb = (unsigned short*)(ws + 65536);  // 32 KB
  float* Sdiag = (float*)(ws + 98304);                 // 128 B
  unsigned short* Sbg = (unsigned short*)(ws + 98432); // 1920 B
  float* inv1 = (float*)(ws + 100352);                 // 3 KB
  float* inv2 = (float*)(ws + 103424);                 // 3 KB

  prep_kernel<<<33, 256, 0, stream>>>(A, w_vec, wf, wb, Sdiag, Sbg);
  norm_kernel<<<(N1 + N2) / 8, 128, 0, stream>>>(X1, X2, Sdiag, wf, inv1, inv2, a);
  main_kernel<<<dim3(N2 / 16, N1 / 16), 512, 0, stream>>>(X1, X2, wb, Sbg, inv1, inv2, out);
}

// Round 13
// 55.832 us; speedup vs baseline: 1.3187x; 1.2078x over previous
//
#include <hip/hip_runtime.h>
#include <hip/hip_bf16.h>

typedef __attribute__((ext_vector_type(8))) short short8;
typedef __attribute__((ext_vector_type(4))) float f32x4;
typedef unsigned long long ull;

#define N1 768
#define N2 768
#define LL 128
#define NS 30

// float -> bf16 bits, round-to-nearest-even (proven rounds 1-12)
__device__ __forceinline__ unsigned short f2b(float f) {
  unsigned int u = __float_as_uint(f);
  unsigned int r = (u + 0x7fffu + ((u >> 16) & 1u)) >> 16;
  return (unsigned short)r;
}

// ---------------------------------------------------------------------------
// aux: ONE launch replaces prep+norm (saves a launch gap + overlaps them).
//  blocks 0..32  (prep role): b==0 -> Sbg = bf16 A@A^T table (stride 32);
//                             b>=1 -> wb = bf16 sigmoid(W).
//  blocks 33..224 (norm role): fully self-sufficient per block:
//    sdg[s]=||A[s]||^2 (30 tiny dots), wfull = f32 sigmoid(W) in LDS
//    (lower-tri expf + mirror; bit-identical to old prep), then the
//    round-8-proven 8-rows-per-block dot/reduce -> inv1/inv2.
// ---------------------------------------------------------------------------
__global__ __launch_bounds__(256) void aux_kernel(
    const int* __restrict__ X1, const int* __restrict__ X2,
    const float* __restrict__ A, const float* __restrict__ w_vec,
    const float* __restrict__ a_ptr, unsigned short* __restrict__ wb,
    unsigned short* __restrict__ Sbg, float* __restrict__ inv1,
    float* __restrict__ inv2) {
  __shared__ __align__(16) float wfull[128][132];  // 67.6 KB (norm role)
  __shared__ __align__(16) float d[8][132];
  __shared__ float sdg[32];
  __shared__ float wsum[4][4];

  const int b = blockIdx.x, t = threadIdx.x;

  if (b < 33) {  // ---- prep role ----
    if (b == 0) {
      for (int idx = t; idx < NS * NS; idx += 256) {
        int i = idx / NS, j = idx - i * NS;
        float acc = 0.f;
#pragma unroll
        for (int k = 0; k < 16; ++k) acc += A[i * 16 + k] * A[j * 16 + k];
        Sbg[i * 32 + j] = f2b(acc);
      }
    } else {
      int base = (b - 1) * 512;
#pragma unroll
      for (int k = 0; k < 2; ++k) {
        int idx = base + k * 256 + t;
        int l = idx >> 7, mm = idx & (LL - 1);
        float sig;
        if (l == mm) {
          sig = 0.5f;
        } else {
          int hi = l > mm ? l : mm, lo = l > mm ? mm : l;
          sig = 1.f / (1.f + expf(-w_vec[hi * (hi - 1) / 2 + lo]));
        }
        wb[idx] = f2b(sig);
      }
    }
    return;
  }

  // ---- norm role ----
  const int r0 = (b - 33) * 8;
  const int wave = t >> 6, h = t >> 7, tl = t & 127, lane = t & 63;

  // phase A: sdg + self-computed sigmoid matrix
  if (t < NS) {
    float acc = 0.f;
#pragma unroll
    for (int c = 0; c < 16; ++c) { float v = A[t * 16 + c]; acc += v * v; }
    sdg[t] = acc;
  }
  if (t < 128) {
    const float* src = w_vec + t * (t - 1) / 2;
    wfull[t][t] = 0.5f;
    for (int mm = 0; mm < t; ++mm) {
      float sig = 1.f / (1.f + expf(-src[mm]));
      wfull[t][mm] = sig;
      wfull[mm][t] = sig;
    }
  }
  __syncthreads();

  // phase B: stage d rows (8 rows x 128 cols)
  if (t < 128) {
#pragma unroll
    for (int r = 0; r < 8; ++r) {
      int row = r0 + r;
      const int* X = (row < N1) ? (X1 + row * LL) : (X2 + (row - N1) * LL);
      d[r][t] = sdg[X[t]];
    }
  }
  __syncthreads();

  // dot: thread (h,tl) owns w-row tl, accumulates rows h*4..h*4+3
  const float4* w4 = reinterpret_cast<const float4*>(&wfull[tl][0]);
  float s[4] = {0.f, 0.f, 0.f, 0.f};
#pragma unroll 8
  for (int q = 0; q < 32; ++q) {
    float4 wv = w4[q];
#pragma unroll
    for (int r = 0; r < 4; ++r) {
      float4 dd = *reinterpret_cast<const float4*>(&d[h * 4 + r][q * 4]);
      s[r] += wv.x * dd.x + wv.y * dd.y + wv.z * dd.z + wv.w * dd.w;
    }
  }
#pragma unroll
  for (int r = 0; r < 4; ++r) {
    float v = s[r] * d[h * 4 + r][tl];
    v += __shfl_xor(v, 1);
    v += __shfl_xor(v, 2);
    v += __shfl_xor(v, 4);
    v += __shfl_xor(v, 8);
    v += __shfl_xor(v, 16);
    v += __shfl_xor(v, 32);
    if (lane == 0) wsum[wave][r] = v;
  }
  __syncthreads();
  if (t < 8) {
    int hh = t >> 2, r = t & 3;
    float k = wsum[hh * 2][r] + wsum[hh * 2 + 1][r];
    int row = r0 + t;
    if (row < N1) inv1[row] = a_ptr[0] * a_ptr[0] / sqrtf(k);
    else inv2[row - N1] = 1.f / sqrtf(k);
  }
}

// ---------------------------------------------------------------------------
// main: EXACT round-9 structure (proven 41.2 us, VGPR 52, wreg resident)
//  + s_setprio(1) around phase 3 (T5: 2 independent blocks/CU co-resident,
//    the attn-like regime where setprio measured +4-7%).
// ---------------------------------------------------------------------------
__global__ __launch_bounds__(512, 4) void main_kernel(
    const int* __restrict__ X1, const int* __restrict__ X2,
    const unsigned short* __restrict__ wbg, const unsigned short* __restrict__ Sbg,
    const float* __restrict__ inv1, const float* __restrict__ inv2,
    float* __restrict__ out) {
  __shared__ __align__(16) unsigned short sV[256 * LL];  // 64 KB, swizzled
  __shared__ __align__(16) unsigned short sSb[960];      // 1920 B S-table (stride 32)
  __shared__ __align__(16) unsigned char x1B[16 * 144];  // bytes [row][l]
  __shared__ __align__(16) unsigned char x2B[16 * 144];
  __shared__ __align__(16) float red[4 * 256];           // cross-lg partials

  const int t = threadIdx.x;
  const int lane = t & 63, wave = t >> 6;
  const int m = lane & 15, kg = lane >> 4;
  const int i0 = blockIdx.y * 16, j0 = blockIdx.x * 16;
  char* sVb = reinterpret_cast<char*>(sV);

  // ---- per-output normalization scalars ----
  float iv1v = 0.f, iv2v = 0.f;
  if (t < 256) {
    iv1v = inv1[i0 + (t >> 4)];
    iv2v = inv2[j0 + (t & 15)];
  }

  // ---- stage bf16 S-table (1920 B = 120 uint4) ----
  if (t < 120) reinterpret_cast<uint4*>(sSb)[t] = reinterpret_cast<const uint4*>(Sbg)[t];

  // ---- stage X rows as bytes [row][l], stride 144 (16-aligned) ----
  if (t < 256) {
    int row = t >> 4, seg = t & 15;
    const int4* p1 = reinterpret_cast<const int4*>(X1 + (i0 + row) * LL + seg * 8);
    int4 a0 = p1[0], a1 = p1[1];
    ull v = 0;
    v |= (ull)(a0.x & 0xff);
    v |= (ull)(a0.y & 0xff) << 8;
    v |= (ull)(a0.z & 0xff) << 16;
    v |= (ull)(a0.w & 0xff) << 24;
    v |= (ull)(a1.x & 0xff) << 32;
    v |= (ull)(a1.y & 0xff) << 40;
    v |= (ull)(a1.z & 0xff) << 48;
    v |= (ull)(a1.w & 0xff) << 56;
    *reinterpret_cast<ull*>(x1B + row * 144 + seg * 8) = v;
    const int4* p2p = reinterpret_cast<const int4*>(X2 + (j0 + row) * LL + seg * 8);
    int4 b0 = p2p[0], b1 = p2p[1];
    ull u = 0;
    u |= (ull)(b0.x & 0xff);
    u |= (ull)(b0.y & 0xff) << 8;
    u |= (ull)(b0.z & 0xff) << 16;
    u |= (ull)(b0.w & 0xff) << 24;
    u |= (ull)(b1.x & 0xff) << 32;
    u |= (ull)(b1.y & 0xff) << 40;
    u |= (ull)(b1.z & 0xff) << 48;
    u |= (ull)(b1.w & 0xff) << 56;
    *reinterpret_cast<ull*>(x2B + row * 144 + seg * 8) = u;
  }
  __syncthreads();

  // ---- phase 2: gather V-build. thread owns pair p2=t&255, l-half h2 ----
  {
    const int p2 = t & 255;
    const int h2 = t >> 8;
    const char* a1p = reinterpret_cast<const char*>(x1B) + (p2 >> 4) * 144 + 64 * h2;
    const char* a2p = reinterpret_cast<const char*>(x2B) + (p2 & 15) * 144 + 64 * h2;
    uint4 A0 = *reinterpret_cast<const uint4*>(a1p);
    uint4 A1 = *reinterpret_cast<const uint4*>(a1p + 16);
    uint4 A2 = *reinterpret_cast<const uint4*>(a1p + 32);
    uint4 A3 = *reinterpret_cast<const uint4*>(a1p + 48);
    uint4 B0 = *reinterpret_cast<const uint4*>(a2p);
    uint4 B1 = *reinterpret_cast<const uint4*>(a2p + 16);
    uint4 B2 = *reinterpret_cast<const uint4*>(a2p + 32);
    uint4 B3 = *reinterpret_cast<const uint4*>(a2p + 48);
    const int swz = (p2 & 7) << 4;
    char* wbase = sVb + p2 * 256;
#define QUAD(u1, u2, w0, w1)                                                        \
    {                                                                               \
      unsigned a0_ = (u1) & 255u, a1_ = ((u1) >> 8) & 255u;                         \
      unsigned a2_ = ((u1) >> 16) & 255u, a3_ = (u1) >> 24;                         \
      unsigned b0_ = (u2) & 255u, b1_ = ((u2) >> 8) & 255u;                         \
      unsigned b2_ = ((u2) >> 16) & 255u, b3_ = (u2) >> 24;                         \
      unsigned g0 = sSb[(a0_ << 5) | b0_];                                          \
      unsigned g1 = sSb[(a1_ << 5) | b1_];                                          \
      unsigned g2 = sSb[(a2_ << 5) | b2_];                                          \
      unsigned g3 = sSb[(a3_ << 5) | b3_];                                          \
      w0 = g0 | (g1 << 16);                                                         \
      w1 = g2 | (g3 << 16);                                                         \
    }
#define OCT(o, U1a, U2a, U1b, U2b)                                                  \
    {                                                                               \
      uint4 pk;                                                                     \
      QUAD(U1a, U2a, pk.x, pk.y)                                                    \
      QUAD(U1b, U2b, pk.z, pk.w)                                                    \
      *reinterpret_cast<uint4*>(wbase + ((128 * h2 + 16 * (o)) ^ swz)) = pk;        \
    }
    OCT(0, A0.x, B0.x, A0.y, B0.y)
    OCT(1, A0.z, B0.z, A0.w, B0.w)
    OCT(2, A1.x, B1.x, A1.y, B1.y)
    OCT(3, A1.z, B1.z, A1.w, B1.w)
    OCT(4, A2.x, B2.x, A2.y, B2.y)
    OCT(5, A2.z, B2.z, A2.w, B2.w)
    OCT(6, A3.x, B3.x, A3.y, B3.y)
    OCT(7, A3.z, B3.z, A3.w, B3.w)
#undef OCT
#undef QUAD
  }

  // ---- W slice into registers: 32 VGPRs (round-6/9-proven resident size) ----
  const int lg = wave & 3, ph = wave >> 2;
  short8 wreg[2][4];
  {
    const char* wby = reinterpret_cast<const char*>(wbg);
#pragma unroll
    for (int lt = 0; lt < 2; ++lt)
#pragma unroll
      for (int kk = 0; kk < 4; ++kk)
        wreg[lt][kk] = *reinterpret_cast<const short8*>(
            wby + (lg * 32 + lt * 16 + m) * 256 + kk * 64 + kg * 16);
  }
  __syncthreads();

  // ---- phase 3: E^T slice = W[lg's 32 rows] @ V^T, folded epilogue ----
  __builtin_amdgcn_s_setprio(1);
#pragma unroll
  for (int pt = 0; pt < 8; ++pt) {
    const int p = ph * 128 + pt * 16 + m;
    const int sw = (p & 7) << 4;
    const char* base = sVb + p * 256;
    short8 bv[4];
#pragma unroll
    for (int kk = 0; kk < 4; ++kk)
      bv[kk] = *reinterpret_cast<const short8*>(base + ((kk * 64 + kg * 16) ^ sw));
    f32x4 a0 = {0.f, 0.f, 0.f, 0.f}, a1 = {0.f, 0.f, 0.f, 0.f};
#pragma unroll
    for (int kk = 0; kk < 4; ++kk) {
      a0 = __builtin_amdgcn_mfma_f32_16x16x32_bf16(wreg[0][kk], bv[kk], a0, 0, 0, 0);
      a1 = __builtin_amdgcn_mfma_f32_16x16x32_bf16(wreg[1][kk], bv[kk], a1, 0, 0, 0);
    }
    float kp = 0.f;
    {
      uint2 vv = *reinterpret_cast<const uint2*>(base + ((64 * lg + 8 * kg) ^ sw));
      kp += a0[0] * __uint_as_float(vv.x << 16) + a0[1] * __uint_as_float(vv.x & 0xffff0000u) +
            a0[2] * __uint_as_float(vv.y << 16) + a0[3] * __uint_as_float(vv.y & 0xffff0000u);
    }
    {
      uint2 vv = *reinterpret_cast<const uint2*>(base + ((64 * lg + 32 + 8 * kg) ^ sw));
      kp += a1[0] * __uint_as_float(vv.x << 16) + a1[1] * __uint_as_float(vv.x & 0xffff0000u) +
            a1[2] * __uint_as_float(vv.y << 16) + a1[3] * __uint_as_float(vv.y & 0xffff0000u);
    }
    kp += __shfl_xor(kp, 16);
    kp += __shfl_xor(kp, 32);
    if (kg == 0) red[lg * 256 + p] = kp;
  }
  __builtin_amdgcn_s_setprio(0);
  __syncthreads();

  // ---- final: cross-lg sum, fused normalization, store ----
  if (t < 256) {
    float s = red[t] + red[256 + t] + red[512 + t] + red[768 + t];
    out[(i0 + (t >> 4)) * N2 + j0 + (t & 15)] = s * iv1v * iv2v;
  }
}

// ---------------------------------------------------------------------------
extern "C" void kernel_launch(void* const* d_in, const int* in_sizes, int n_in,
                              void* d_out, int out_size, void* d_ws, size_t ws_size,
                              hipStream_t stream) {
  const int* X1 = (const int*)d_in[0];
  const int* X2 = (const int*)d_in[1];
  const float* a = (const float*)d_in[2];
  const float* A = (const float*)d_in[3];
  const float* w_vec = (const float*)d_in[4];
  float* out = (float*)d_out;

  char* ws = (char*)d_ws;
  unsigned short* wb = (unsigned short*)(ws + 0);      // 32 KB
  unsigned short* Sbg = (unsigned short*)(ws + 32768); // 1920 B (pad to 4 KB)
  float* inv1 = (float*)(ws + 36864);                  // 3 KB
  float* inv2 = (float*)(ws + 39936);                  // 3 KB

  aux_kernel<<<225, 256, 0, stream>>>(X1, X2, A, w_vec, a, wb, Sbg, inv1, inv2);
  main_kernel<<<dim3(N2 / 16, N1 / 16), 512, 0, stream>>>(X1, X2, wb, Sbg, inv1, inv2, out);
}

// Round 14
// 46.707 us; speedup vs baseline: 1.5764x; 1.1954x over previous
//
#include <hip/hip_runtime.h>
#include <hip/hip_bf16.h>

typedef __attribute__((ext_vector_type(8))) short short8;
typedef __attribute__((ext_vector_type(4))) float f32x4;
typedef unsigned long long ull;

#define N1 768
#define N2 768
#define LL 128
#define NS 30

// float -> bf16 bits, round-to-nearest-even (proven rounds 1-13)
__device__ __forceinline__ unsigned short f2b(float f) {
  unsigned int u = __float_as_uint(f);
  unsigned int r = (u + 0x7fffu + ((u >> 16) & 1u)) >> 16;
  return (unsigned short)r;
}

// ---------------------------------------------------------------------------
// aux: ONE launch replaces prep+norm.
//  blocks 0..32  (prep role): b==0 -> Sbg = bf16 A@A^T table (stride 32);
//                             b>=1 -> wb = bf16 sigmoid(W).
//  blocks 33..224 (norm role): self-sufficient:
//    sigmoid W built BALANCED: 8128 tri entries / 256 threads = 32 expf each
//    (round-13 regression: per-row loop made thread 127 do 127 SERIAL expf).
//    (hi,lo) from flat index via exact-f32 sqrt + increment walk.
//    Then round-8-proven 8-rows-per-block dot/reduce -> inv1/inv2.
// ---------------------------------------------------------------------------
__global__ __launch_bounds__(256) void aux_kernel(
    const int* __restrict__ X1, const int* __restrict__ X2,
    const float* __restrict__ A, const float* __restrict__ w_vec,
    const float* __restrict__ a_ptr, unsigned short* __restrict__ wb,
    unsigned short* __restrict__ Sbg, float* __restrict__ inv1,
    float* __restrict__ inv2) {
  __shared__ __align__(16) float wfull[128][132];  // 67.6 KB (norm role)
  __shared__ __align__(16) float d[8][132];
  __shared__ float sdg[32];
  __shared__ float wsum[4][4];

  const int b = blockIdx.x, t = threadIdx.x;

  if (b < 33) {  // ---- prep role ----
    if (b == 0) {
      for (int idx = t; idx < NS * NS; idx += 256) {
        int i = idx / NS, j = idx - i * NS;
        float acc = 0.f;
#pragma unroll
        for (int k = 0; k < 16; ++k) acc += A[i * 16 + k] * A[j * 16 + k];
        Sbg[i * 32 + j] = f2b(acc);
      }
    } else {
      int base = (b - 1) * 512;
#pragma unroll
      for (int k = 0; k < 2; ++k) {
        int idx = base + k * 256 + t;
        int l = idx >> 7, mm = idx & (LL - 1);
        float sig;
        if (l == mm) {
          sig = 0.5f;
        } else {
          int hi = l > mm ? l : mm, lo = l > mm ? mm : l;
          sig = 1.f / (1.f + expf(-w_vec[hi * (hi - 1) / 2 + lo]));
        }
        wb[idx] = f2b(sig);
      }
    }
    return;
  }

  // ---- norm role ----
  const int r0 = (b - 33) * 8;
  const int wave = t >> 6, h = t >> 7, tl = t & 127, lane = t & 63;

  // phase A: sdg + BALANCED sigmoid matrix (32 expf/thread, parallel)
  if (t < NS) {
    float acc = 0.f;
#pragma unroll
    for (int c = 0; c < 16; ++c) { float v = A[t * 16 + c]; acc += v * v; }
    sdg[t] = acc;
  }
  {
    const int NTRI = LL * (LL - 1) / 2;  // 8128
    int k0 = t * 32;
    if (k0 < NTRI) {
      int kend = k0 + 32 < NTRI ? k0 + 32 : NTRI;
      int hi = (int)((sqrtf(8.f * (float)k0 + 1.f) + 1.f) * 0.5f);
      while (hi * (hi - 1) / 2 > k0) --hi;           // guard f32 rounding
      while ((hi + 1) * hi / 2 <= k0) ++hi;
      int lo = k0 - hi * (hi - 1) / 2;
      for (int k = k0; k < kend; ++k) {
        float sig = 1.f / (1.f + expf(-w_vec[k]));
        wfull[hi][lo] = sig;
        wfull[lo][hi] = sig;
        if (++lo == hi) { lo = 0; ++hi; }
      }
    }
    if (t < 128) wfull[t][t] = 0.5f;
  }
  __syncthreads();

  // phase B: stage d rows (8 rows x 128 cols)
  if (t < 128) {
#pragma unroll
    for (int r = 0; r < 8; ++r) {
      int row = r0 + r;
      const int* X = (row < N1) ? (X1 + row * LL) : (X2 + (row - N1) * LL);
      d[r][t] = sdg[X[t]];
    }
  }
  __syncthreads();

  // dot: thread (h,tl) owns w-row tl, accumulates rows h*4..h*4+3
  const float4* w4 = reinterpret_cast<const float4*>(&wfull[tl][0]);
  float s[4] = {0.f, 0.f, 0.f, 0.f};
#pragma unroll 8
  for (int q = 0; q < 32; ++q) {
    float4 wv = w4[q];
#pragma unroll
    for (int r = 0; r < 4; ++r) {
      float4 dd = *reinterpret_cast<const float4*>(&d[h * 4 + r][q * 4]);
      s[r] += wv.x * dd.x + wv.y * dd.y + wv.z * dd.z + wv.w * dd.w;
    }
  }
#pragma unroll
  for (int r = 0; r < 4; ++r) {
    float v = s[r] * d[h * 4 + r][tl];
    v += __shfl_xor(v, 1);
    v += __shfl_xor(v, 2);
    v += __shfl_xor(v, 4);
    v += __shfl_xor(v, 8);
    v += __shfl_xor(v, 16);
    v += __shfl_xor(v, 32);
    if (lane == 0) wsum[wave][r] = v;
  }
  __syncthreads();
  if (t < 8) {
    int hh = t >> 2, r = t & 3;
    float k = wsum[hh * 2][r] + wsum[hh * 2 + 1][r];
    int row = r0 + t;
    if (row < N1) inv1[row] = a_ptr[0] * a_ptr[0] / sqrtf(k);
    else inv2[row - N1] = 1.f / sqrtf(k);
  }
}

// ---------------------------------------------------------------------------
// main: EXACT round-13 structure (proven 40.7 us, VGPR 52, wreg resident):
//  round-9 phases + s_setprio(1) around phase 3.
// ---------------------------------------------------------------------------
__global__ __launch_bounds__(512, 4) void main_kernel(
    const int* __restrict__ X1, const int* __restrict__ X2,
    const unsigned short* __restrict__ wbg, const unsigned short* __restrict__ Sbg,
    const float* __restrict__ inv1, const float* __restrict__ inv2,
    float* __restrict__ out) {
  __shared__ __align__(16) unsigned short sV[256 * LL];  // 64 KB, swizzled
  __shared__ __align__(16) unsigned short sSb[960];      // 1920 B S-table (stride 32)
  __shared__ __align__(16) unsigned char x1B[16 * 144];  // bytes [row][l]
  __shared__ __align__(16) unsigned char x2B[16 * 144];
  __shared__ __align__(16) float red[4 * 256];           // cross-lg partials

  const int t = threadIdx.x;
  const int lane = t & 63, wave = t >> 6;
  const int m = lane & 15, kg = lane >> 4;
  const int i0 = blockIdx.y * 16, j0 = blockIdx.x * 16;
  char* sVb = reinterpret_cast<char*>(sV);

  // ---- per-output normalization scalars ----
  float iv1v = 0.f, iv2v = 0.f;
  if (t < 256) {
    iv1v = inv1[i0 + (t >> 4)];
    iv2v = inv2[j0 + (t & 15)];
  }

  // ---- stage bf16 S-table (1920 B = 120 uint4) ----
  if (t < 120) reinterpret_cast<uint4*>(sSb)[t] = reinterpret_cast<const uint4*>(Sbg)[t];

  // ---- stage X rows as bytes [row][l], stride 144 (16-aligned) ----
  if (t < 256) {
    int row = t >> 4, seg = t & 15;
    const int4* p1 = reinterpret_cast<const int4*>(X1 + (i0 + row) * LL + seg * 8);
    int4 a0 = p1[0], a1 = p1[1];
    ull v = 0;
    v |= (ull)(a0.x & 0xff);
    v |= (ull)(a0.y & 0xff) << 8;
    v |= (ull)(a0.z & 0xff) << 16;
    v |= (ull)(a0.w & 0xff) << 24;
    v |= (ull)(a1.x & 0xff) << 32;
    v |= (ull)(a1.y & 0xff) << 40;
    v |= (ull)(a1.z & 0xff) << 48;
    v |= (ull)(a1.w & 0xff) << 56;
    *reinterpret_cast<ull*>(x1B + row * 144 + seg * 8) = v;
    const int4* p2p = reinterpret_cast<const int4*>(X2 + (j0 + row) * LL + seg * 8);
    int4 b0 = p2p[0], b1 = p2p[1];
    ull u = 0;
    u |= (ull)(b0.x & 0xff);
    u |= (ull)(b0.y & 0xff) << 8;
    u |= (ull)(b0.z & 0xff) << 16;
    u |= (ull)(b0.w & 0xff) << 24;
    u |= (ull)(b1.x & 0xff) << 32;
    u |= (ull)(b1.y & 0xff) << 40;
    u |= (ull)(b1.z & 0xff) << 48;
    u |= (ull)(b1.w & 0xff) << 56;
    *reinterpret_cast<ull*>(x2B + row * 144 + seg * 8) = u;
  }
  __syncthreads();

  // ---- phase 2: gather V-build. thread owns pair p2=t&255, l-half h2 ----
  {
    const int p2 = t & 255;
    const int h2 = t >> 8;
    const char* a1p = reinterpret_cast<const char*>(x1B) + (p2 >> 4) * 144 + 64 * h2;
    const char* a2p = reinterpret_cast<const char*>(x2B) + (p2 & 15) * 144 + 64 * h2;
    uint4 A0 = *reinterpret_cast<const uint4*>(a1p);
    uint4 A1 = *reinterpret_cast<const uint4*>(a1p + 16);
    uint4 A2 = *reinterpret_cast<const uint4*>(a1p + 32);
    uint4 A3 = *reinterpret_cast<const uint4*>(a1p + 48);
    uint4 B0 = *reinterpret_cast<const uint4*>(a2p);
    uint4 B1 = *reinterpret_cast<const uint4*>(a2p + 16);
    uint4 B2 = *reinterpret_cast<const uint4*>(a2p + 32);
    uint4 B3 = *reinterpret_cast<const uint4*>(a2p + 48);
    const int swz = (p2 & 7) << 4;
    char* wbase = sVb + p2 * 256;
#define QUAD(u1, u2, w0, w1)                                                        \
    {                                                                               \
      unsigned a0_ = (u1) & 255u, a1_ = ((u1) >> 8) & 255u;                         \
      unsigned a2_ = ((u1) >> 16) & 255u, a3_ = (u1) >> 24;                         \
      unsigned b0_ = (u2) & 255u, b1_ = ((u2) >> 8) & 255u;                         \
      unsigned b2_ = ((u2) >> 16) & 255u, b3_ = (u2) >> 24;                         \
      unsigned g0 = sSb[(a0_ << 5) | b0_];                                          \
      unsigned g1 = sSb[(a1_ << 5) | b1_];                                          \
      unsigned g2 = sSb[(a2_ << 5) | b2_];                                          \
      unsigned g3 = sSb[(a3_ << 5) | b3_];                                          \
      w0 = g0 | (g1 << 16);                                                         \
      w1 = g2 | (g3 << 16);                                                         \
    }
#define OCT(o, U1a, U2a, U1b, U2b)                                                  \
    {                                                                               \
      uint4 pk;                                                                     \
      QUAD(U1a, U2a, pk.x, pk.y)                                                    \
      QUAD(U1b, U2b, pk.z, pk.w)                                                    \
      *reinterpret_cast<uint4*>(wbase + ((128 * h2 + 16 * (o)) ^ swz)) = pk;        \
    }
    OCT(0, A0.x, B0.x, A0.y, B0.y)
    OCT(1, A0.z, B0.z, A0.w, B0.w)
    OCT(2, A1.x, B1.x, A1.y, B1.y)
    OCT(3, A1.z, B1.z, A1.w, B1.w)
    OCT(4, A2.x, B2.x, A2.y, B2.y)
    OCT(5, A2.z, B2.z, A2.w, B2.w)
    OCT(6, A3.x, B3.x, A3.y, B3.y)
    OCT(7, A3.z, B3.z, A3.w, B3.w)
#undef OCT
#undef QUAD
  }

  // ---- W slice into registers: 32 VGPRs (round-6/9-proven resident size) ----
  const int lg = wave & 3, ph = wave >> 2;
  short8 wreg[2][4];
  {
    const char* wby = reinterpret_cast<const char*>(wbg);
#pragma unroll
    for (int lt = 0; lt < 2; ++lt)
#pragma unroll
      for (int kk = 0; kk < 4; ++kk)
        wreg[lt][kk] = *reinterpret_cast<const short8*>(
            wby + (lg * 32 + lt * 16 + m) * 256 + kk * 64 + kg * 16);
  }
  __syncthreads();

  // ---- phase 3: E^T slice = W[lg's 32 rows] @ V^T, folded epilogue ----
  __builtin_amdgcn_s_setprio(1);
#pragma unroll
  for (int pt = 0; pt < 8; ++pt) {
    const int p = ph * 128 + pt * 16 + m;
    const int sw = (p & 7) << 4;
    const char* base = sVb + p * 256;
    short8 bv[4];
#pragma unroll
    for (int kk = 0; kk < 4; ++kk)
      bv[kk] = *reinterpret_cast<const short8*>(base + ((kk * 64 + kg * 16) ^ sw));
    f32x4 a0 = {0.f, 0.f, 0.f, 0.f}, a1 = {0.f, 0.f, 0.f, 0.f};
#pragma unroll
    for (int kk = 0; kk < 4; ++kk) {
      a0 = __builtin_amdgcn_mfma_f32_16x16x32_bf16(wreg[0][kk], bv[kk], a0, 0, 0, 0);
      a1 = __builtin_amdgcn_mfma_f32_16x16x32_bf16(wreg[1][kk], bv[kk], a1, 0, 0, 0);
    }
    float kp = 0.f;
    {
      uint2 vv = *reinterpret_cast<const uint2*>(base + ((64 * lg + 8 * kg) ^ sw));
      kp += a0[0] * __uint_as_float(vv.x << 16) + a0[1] * __uint_as_float(vv.x & 0xffff0000u) +
            a0[2] * __uint_as_float(vv.y << 16) + a0[3] * __uint_as_float(vv.y & 0xffff0000u);
    }
    {
      uint2 vv = *reinterpret_cast<const uint2*>(base + ((64 * lg + 32 + 8 * kg) ^ sw));
      kp += a1[0] * __uint_as_float(vv.x << 16) + a1[1] * __uint_as_float(vv.x & 0xffff0000u) +
            a1[2] * __uint_as_float(vv.y << 16) + a1[3] * __uint_as_float(vv.y & 0xffff0000u);
    }
    kp += __shfl_xor(kp, 16);
    kp += __shfl_xor(kp, 32);
    if (kg == 0) red[lg * 256 + p] = kp;
  }
  __builtin_amdgcn_s_setprio(0);
  __syncthreads();

  // ---- final: cross-lg sum, fused normalization, store ----
  if (t < 256) {
    float s = red[t] + red[256 + t] + red[512 + t] + red[768 + t];
    out[(i0 + (t >> 4)) * N2 + j0 + (t & 15)] = s * iv1v * iv2v;
  }
}

// ---------------------------------------------------------------------------
extern "C" void kernel_launch(void* const* d_in, const int* in_sizes, int n_in,
                              void* d_out, int out_size, void* d_ws, size_t ws_size,
                              hipStream_t stream) {
  const int* X1 = (const int*)d_in[0];
  const int* X2 = (const int*)d_in[1];
  const float* a = (const float*)d_in[2];
  const float* A = (const float*)d_in[3];
  const float* w_vec = (const float*)d_in[4];
  float* out = (float*)d_out;

  char* ws = (char*)d_ws;
  unsigned short* wb = (unsigned short*)(ws + 0);      // 32 KB
  unsigned short* Sbg = (unsigned short*)(ws + 32768); // 1920 B (pad to 4 KB)
  float* inv1 = (float*)(ws + 36864);                  // 3 KB
  float* inv2 = (float*)(ws + 39936);                  // 3 KB

  aux_kernel<<<225, 256, 0, stream>>>(X1, X2, A, w_vec, a, wb, Sbg, inv1, inv2);
  main_kernel<<<dim3(N2 / 16, N1 / 16), 512, 0, stream>>>(X1, X2, wb, Sbg, inv1, inv2, out);
}